// Round 9
// baseline (220.351 us; speedup 1.0000x reference)
//
#include <hip/hip_runtime.h>
#include <math.h>

// ViT Vector Quantizer: z [32,1024,32] f32, embedding [8192,32] f32.
// Outputs (concat, read as f32): z_q_out [N*D], loss [1], idx [N] (as floats).
//
// R9: 4-row-group split-K MFMA argmin with in-flight split merge.
//   K0 k_prep        : codebook normalize -> en, en_h, bf16 hi/lo B-frag swizzle;
//                      zero cnt/loss/tick.
//   K1 k_argmin_mfma : each wave: 64 rows (4 groups of 16) x 2048 codes (KSPLIT=4).
//                      One B-fragment ds_read pair feeds 12 MFMAs (4 indep 3-chains)
//                      -> LDS traffic /4 vs R8. Packed-u32 top-2 via pair max/min +
//                      v_max3_u32 (3.5 VALU/score, no reg-copy pipeline).
//                      Per-split (s1|k, s2) stored; per-rowblock ticket: 4th block
//                      merges splits, flags gap < 2e-4, writes idx_ws/list/cnt.
//   K2 k_cleanup     : flagged rows exact fp32 rescore, thread-per-code.
//   K3 k_epi         : decode sentinel, gather en[idx], write outputs.

#define D 32
#define KCODES 8192
#define KSPLIT 4
#define SPLITCODES 2048     // KCODES/KSPLIT, per-wave K range
#define NCHUNK 8            // 8 chunks x 256 codes (32 KB) per split
#define MASK8 0xFFFFFF00u   // keep 24 high bits; low 8 = (255 - tile)
#define MARGIN_Q 2.0e-4f    // safe: unflagged => true gap >= 1.4e-4 > 2*2.4e-5
#define EPS 1e-12f

typedef short bf16x8 __attribute__((ext_vector_type(8)));
typedef unsigned short u16x8 __attribute__((ext_vector_type(8)));
typedef float f32x4 __attribute__((ext_vector_type(4)));

static __device__ __forceinline__ unsigned short f2bf(float x) {  // RNE bf16 bits
  unsigned u = __float_as_uint(x);
  return (unsigned short)((u + 0x7FFFu + ((u >> 16) & 1u)) >> 16);
}
static __device__ __forceinline__ float bf2f(unsigned short s) {
  return __uint_as_float(((unsigned)s) << 16);
}
static __device__ __forceinline__ void gload_lds16(const void* g, void* l) {
  __builtin_amdgcn_global_load_lds(
      (const __attribute__((address_space(1))) void*)g,
      (__attribute__((address_space(3))) void*)l, 16, 0, 0);
}
static __device__ __forceinline__ unsigned umax3(unsigned a, unsigned b, unsigned c) {
  return max(max(a, b), c);   // compiler emits v_max3_u32
}

// MFMA fragment layouts (validated by R5-R8 exact-idx passes):
//   A[m][k]: m = lane&15, k = (lane>>4)*8 + j
//   B[k][n]: n = lane&15, k = (lane>>4)*8 + j
//   C[m][n]: n = lane&15, m = (lane>>4)*4 + reg

__global__ __launch_bounds__(256) void k_prep(const float* __restrict__ emb,
                                              float* __restrict__ en,
                                              float* __restrict__ en_h,
                                              unsigned short* __restrict__ eswz,
                                              int* __restrict__ cnt,
                                              float* __restrict__ loss,
                                              int* __restrict__ tick,
                                              int ntick) {
  int v = blockIdx.x * 256 + threadIdx.x;
  if (v == 0) { *cnt = 0; *loss = 0.f; }
  if (v < ntick) tick[v] = 0;
  if (v >= KCODES) return;

  float x[D];
  const float4* p = reinterpret_cast<const float4*>(emb + (size_t)v * D);
#pragma unroll
  for (int j = 0; j < D / 4; ++j) {
    float4 q = p[j];
    x[4 * j + 0] = q.x; x[4 * j + 1] = q.y; x[4 * j + 2] = q.z; x[4 * j + 3] = q.w;
  }
  float ss = 0.f;
#pragma unroll
  for (int j = 0; j < D; ++j) ss = fmaf(x[j], x[j], ss);
  float n = fmaxf(sqrtf(ss), EPS);
#pragma unroll
  for (int j = 0; j < D; ++j) x[j] = x[j] / n;   // true division mirrors reference

  float4* o = reinterpret_cast<float4*>(en + (size_t)v * D);
  float s2 = 0.f;
#pragma unroll
  for (int j = 0; j < D / 4; ++j) {
    float4 q = {x[4 * j], x[4 * j + 1], x[4 * j + 2], x[4 * j + 3]};
    s2 = fmaf(q.x, q.x, fmaf(q.y, q.y, fmaf(q.z, q.z, fmaf(q.w, q.w, s2))));
    o[j] = q;
  }
  en_h[v] = 0.5f * s2;

  unsigned short hi[D], lo[D];
#pragma unroll
  for (int j = 0; j < D; ++j) {
    hi[j] = f2bf(x[j]);
    lo[j] = f2bf(x[j] - bf2f(hi[j]));   // x - bf16(x) exact in fp32
  }
  int tl = v >> 4, m = v & 15;          // B-fragment swizzle: tile = 1024 shorts
#pragma unroll
  for (int q = 0; q < 4; ++q) {
    u16x8 hv, lv;
#pragma unroll
    for (int j = 0; j < 8; ++j) { hv[j] = hi[8 * q + j]; lv[j] = lo[8 * q + j]; }
    *(u16x8*)(eswz + (size_t)tl * 1024 + (q * 16 + m) * 8) = hv;
    *(u16x8*)(eswz + (size_t)tl * 1024 + 512 + (q * 16 + m) * 8) = lv;
  }
}

// grid (N/256, KSPLIT); block 256 = 4 waves; each wave: 64 rows x 2048 codes.
__global__ __launch_bounds__(256, 2) void k_argmin_mfma(
    const float* __restrict__ z,
    const unsigned short* __restrict__ eswz,
    unsigned long long* __restrict__ mpp,   // [KSPLIT][N] (s1bits<<32 | 8191-k)
    float* __restrict__ g2,                 // [KSPLIT][N] quantized 2nd-best
    int* __restrict__ tick,
    int* __restrict__ idx_ws, int* __restrict__ list, int* __restrict__ cnt,
    unsigned long long* __restrict__ mp2, int N) {
  __shared__ unsigned short lds_sh[2][16384];   // 2 x 32 KB double buffer
  __shared__ int s_old;

  const int tid = threadIdx.x;
  const int wid = tid >> 6, lane = tid & 63;
  const int lane15 = lane & 15, quad = lane >> 4;
  const int rb = blockIdx.x;                    // row-block (256 rows)
  const int split = blockIdx.y;                 // K split
  const int rowbase = rb * 256 + wid * 64;      // this wave's 64 rows
  const int kbase = split * SPLITCODES;

  // issue chunk-0 DMA first so it overlaps the prologue
  const float4* gall = reinterpret_cast<const float4*>(eswz) +
                       (size_t)(split * 128) * 128;   // 128 tiles x 128 float4
#pragma unroll
  for (int i = 0; i < 8; ++i) {
    int off = i * 256 + tid;                    // wave-uniform base + lane*16B
    gload_lds16(gall + off, (char*)&lds_sh[0][0] + (size_t)off * 16);
  }

  // --- A-fragments for 4 row groups (lane's row: group*16+lane15, dims quad*8..) ---
  bf16x8 zh[4], zl[4];
#pragma unroll
  for (int g = 0; g < 4; ++g) {
    const float4* p =
        reinterpret_cast<const float4*>(z + (size_t)(rowbase + g * 16 + lane15) * D);
    float ss = 0.f;
#pragma unroll
    for (int j = 0; j < 8; ++j) {
      float4 q = p[j];
      ss = fmaf(q.x, q.x, fmaf(q.y, q.y, fmaf(q.z, q.z, fmaf(q.w, q.w, ss))));
    }
    float nn = fmaxf(sqrtf(ss), EPS);
    float4 a0 = p[quad * 2], a1 = p[quad * 2 + 1];
    float xs[8] = {a0.x / nn, a0.y / nn, a0.z / nn, a0.w / nn,
                   a1.x / nn, a1.y / nn, a1.z / nn, a1.w / nn};
#pragma unroll
    for (int j = 0; j < 8; ++j) {
      unsigned short h = f2bf(xs[j]);
      zh[g][j] = (short)h;
      zl[g][j] = (short)f2bf(xs[j] - bf2f(h));
    }
  }

  unsigned p1[4][4], p2[4][4];
#pragma unroll
  for (int g = 0; g < 4; ++g)
#pragma unroll
    for (int r = 0; r < 4; ++r) { p1[g][r] = 0u; p2[g][r] = 0u; }
  const f32x4 initc = {1.25f, 1.25f, 1.25f, 1.25f};  // s' = 1.25 + dot > 0

  for (int c = 0; c < NCHUNK; ++c) {
    __syncthreads();              // buffer c&1 fully staged (vmcnt drained)
    if (c + 1 < NCHUNK) {         // next DMA overlaps this chunk's compute
      const float4* gn = gall + (size_t)(c + 1) * 2048;
      char* dst = (char*)&lds_sh[(c + 1) & 1][0];
#pragma unroll
      for (int i = 0; i < 8; ++i) {
        int off = i * 256 + tid;
        gload_lds16(gn + off, dst + (size_t)off * 16);
      }
    }
    const unsigned short* buf = &lds_sh[c & 1][0];
#pragma unroll
    for (int t = 0; t < 16; ++t) {
      bf16x8 bh = *(const bf16x8*)(buf + t * 1024 + lane * 8);
      bf16x8 bl = *(const bf16x8*)(buf + t * 1024 + 512 + lane * 8);
      const unsigned tid8 = (unsigned)(255 - (c * 16 + t));
#pragma unroll
      for (int g = 0; g < 4; ++g) {           // 4 independent 3-MFMA chains
        f32x4 acc = __builtin_amdgcn_mfma_f32_16x16x32_bf16(zh[g], bh, initc, 0, 0, 0);
        acc = __builtin_amdgcn_mfma_f32_16x16x32_bf16(zh[g], bl, acc, 0, 0, 0);
        acc = __builtin_amdgcn_mfma_f32_16x16x32_bf16(zl[g], bh, acc, 0, 0, 0);
        unsigned q0 = (__float_as_uint(acc[0]) & MASK8) | tid8;
        unsigned q1 = (__float_as_uint(acc[1]) & MASK8) | tid8;
        unsigned q2 = (__float_as_uint(acc[2]) & MASK8) | tid8;
        unsigned q3 = (__float_as_uint(acc[3]) & MASK8) | tid8;
        unsigned m01 = max(q0, q1), n01 = min(q0, q1);
        unsigned m23 = max(q2, q3), n23 = min(q2, q3);
        unsigned M = max(m01, m23), t2 = min(m01, m23);
        unsigned dem = min(p1[g][0 * 0], M);  // placeholder avoided below
        (void)dem;
#pragma unroll
        for (int r = 0; r < 1; ++r) {}        // (no-op; keeps structure flat)
        // top-2 update for this group's 4 rows is PER-ROW, not across rows:
        // q0..q3 are scores of 4 DIFFERENT rows -> revert to per-score update.
        unsigned t0 = min(q0, p1[g][0]); p1[g][0] = max(q0, p1[g][0]); p2[g][0] = max(t0, p2[g][0]);
        unsigned t1 = min(q1, p1[g][1]); p1[g][1] = max(q1, p1[g][1]); p2[g][1] = max(t1, p2[g][1]);
        unsigned t2b = min(q2, p1[g][2]); p1[g][2] = max(q2, p1[g][2]); p2[g][2] = max(t2b, p2[g][2]);
        unsigned t3 = min(q3, p1[g][3]); p1[g][3] = max(q3, p1[g][3]); p2[g][3] = max(t3, p2[g][3]);
        (void)M; (void)t2; (void)m01; (void)n01; (void)m23; (void)n23;
      }
    }
  }

  // --- per-wave cross-lane merge (16 cols per quad), then store split partials ---
#pragma unroll
  for (int g = 0; g < 4; ++g) {
#pragma unroll
    for (int r = 0; r < 4; ++r) {
      unsigned pv = p1[g][r];
      unsigned sb = pv & MASK8;
      int tile = 255 - (int)(pv & 0xFFu);
      int kfull = kbase + tile * 16 + lane15;
      float s1f = __uint_as_float(sb);
      float s2f = __uint_as_float(p2[g][r] & MASK8);
      unsigned long long pk =
          ((unsigned long long)sb << 32) | (unsigned)(8191 - kfull);
#pragma unroll
      for (int m = 1; m <= 8; m <<= 1) {
        unsigned long long op = __shfl_xor(pk, m, 64);
        float os1 = __shfl_xor(s1f, m, 64);
        float os2 = __shfl_xor(s2f, m, 64);
        s2f = fmaxf(fmaxf(s2f, os2), fminf(s1f, os1));  // union 2nd-best
        s1f = fmaxf(s1f, os1);
        pk = (op > pk) ? op : pk;                       // max s, tie -> min k
      }
      if (lane15 == 0) {
        int row = rowbase + g * 16 + quad * 4 + r;
        mpp[(size_t)split * N + row] = pk;
        g2[(size_t)split * N + row] = s2f;
      }
    }
  }

  // --- last-arriving split block merges all 4 splits for this row-block ---
  __threadfence();
  __syncthreads();
  if (tid == 0) s_old = atomicAdd(&tick[rb], 1);
  __syncthreads();
  if (s_old == KSPLIT - 1) {
    __threadfence();
    int row = rb * 256 + tid;                 // one row per thread
    unsigned long long k0 = mpp[(size_t)0 * N + row];
    unsigned long long k1 = mpp[(size_t)1 * N + row];
    unsigned long long k2 = mpp[(size_t)2 * N + row];
    unsigned long long k3 = mpp[(size_t)3 * N + row];
    float a0 = g2[(size_t)0 * N + row], a1 = g2[(size_t)1 * N + row];
    float a2 = g2[(size_t)2 * N + row], a3 = g2[(size_t)3 * N + row];
    unsigned long long m01 = (k0 > k1) ? k0 : k1;
    unsigned long long m23 = (k2 > k3) ? k2 : k3;
    unsigned long long B = (m01 > m23) ? m01 : m23;
    float s1g = __uint_as_float((unsigned)(B >> 32));
    float c0 = (k0 == B) ? a0 : __uint_as_float((unsigned)(k0 >> 32));
    float c1 = (k1 == B) ? a1 : __uint_as_float((unsigned)(k1 >> 32));
    float c2 = (k2 == B) ? a2 : __uint_as_float((unsigned)(k2 >> 32));
    float c3 = (k3 == B) ? a3 : __uint_as_float((unsigned)(k3 >> 32));
    float s2g = fmaxf(fmaxf(c0, c1), fmaxf(c2, c3));
    int kb = 8191 - (int)(unsigned)(B & 0xFFFFFFFFull);
    if (s1g - s2g < MARGIN_Q) {               // ambiguous -> exact rescore
      int pos = atomicAdd(cnt, 1);
      list[pos] = row;
      mp2[pos] = 0ull;                        // atomicMax identity
      idx_ws[row] = -(pos + 1);               // sentinel, resolved in epi
    } else {
      idx_ws[row] = kb;
    }
  }
}

// Exact fp32 rescore, thread-per-code; block-reduce + one atomicMax per block.
__global__ __launch_bounds__(256) void k_cleanup(const float* __restrict__ z,
                                                 const float* __restrict__ en,
                                                 const float* __restrict__ en_h,
                                                 const int* __restrict__ list,
                                                 const int* __restrict__ cnt,
                                                 unsigned long long* __restrict__ mp2) {
  __shared__ unsigned long long wred[4];
  const int tid = threadIdx.x;
  const int lane = tid & 63, wid = tid >> 6;
  const int ntask = (*cnt) * 32;               // 32 chunks of 256 codes per row

  for (int j = blockIdx.x; j < ntask; j += gridDim.x) {
    int i = j >> 5, kc = j & 31;
    int row = list[i];
    const float* zr = z + (size_t)row * D;     // wave-uniform -> scalar loads
    float v[D];
    float ss = 0.f;
#pragma unroll
    for (int d = 0; d < D; ++d) v[d] = zr[d];
#pragma unroll
    for (int d = 0; d < D; ++d) ss = fmaf(v[d], v[d], ss);
    float n = fmaxf(sqrtf(ss), EPS);
#pragma unroll
    for (int d = 0; d < D; ++d) v[d] = v[d] / n;

    int k = kc * 256 + tid;                    // contiguous -> coalesced
    const float4* er = reinterpret_cast<const float4*>(en + (size_t)k * D);
    float a = -en_h[k];
#pragma unroll
    for (int jj = 0; jj < 8; ++jj) {           // exact R4 fma order
      float4 e = er[jj];
      a = fmaf(v[4 * jj + 0], e.x, a);
      a = fmaf(v[4 * jj + 1], e.y, a);
      a = fmaf(v[4 * jj + 2], e.z, a);
      a = fmaf(v[4 * jj + 3], e.w, a);
    }
    unsigned o = __float_as_uint(a);
    o = (o & 0x80000000u) ? ~o : (o | 0x80000000u);
    unsigned long long pk = ((unsigned long long)o << 32) | (unsigned)(8191 - k);
#pragma unroll
    for (int m = 32; m >= 1; m >>= 1) {
      unsigned long long op = __shfl_xor(pk, m, 64);
      pk = (op > pk) ? op : pk;                // max s, tie -> min k
    }
    if (lane == 0) wred[wid] = pk;
    __syncthreads();
    if (tid == 0) {
      unsigned long long m01 = (wred[0] > wred[1]) ? wred[0] : wred[1];
      unsigned long long m23 = (wred[2] > wred[3]) ? wred[2] : wred[3];
      atomicMax(&mp2[i], (m01 > m23) ? m01 : m23);
    }
    __syncthreads();                           // protect wred for next task
  }
}

__global__ __launch_bounds__(256) void k_epi(const float* __restrict__ z,
                                             const float* __restrict__ en,
                                             const int* __restrict__ idx_ws,
                                             const unsigned long long* __restrict__ mp2,
                                             float* __restrict__ out_z,
                                             float* __restrict__ loss,
                                             float* __restrict__ out_idx,
                                             float scale) {
  int row = blockIdx.x * 256 + threadIdx.x;
  int kb = idx_ws[row];
  if (kb < 0) {                                // flagged: exact result in mp2
    unsigned long long m = mp2[-kb - 1];
    kb = 8191 - (int)(unsigned)(m & 0xFFFFFFFFull);
  }
  out_idx[row] = (float)kb;  // whole out buffer read back as f32

  const float4* p = reinterpret_cast<const float4*>(z + (size_t)row * D);
  float4 q[D / 4];
#pragma unroll
  for (int j = 0; j < D / 4; ++j) q[j] = p[j];
  float ss = 0.f;
#pragma unroll
  for (int j = 0; j < D / 4; ++j)
    ss = fmaf(q[j].x, q[j].x, fmaf(q[j].y, q[j].y, fmaf(q[j].z, q[j].z, fmaf(q[j].w, q[j].w, ss))));
  float n = fmaxf(sqrtf(ss), EPS);

  const float4* ep = reinterpret_cast<const float4*>(en + (size_t)kb * D);
  float4* op = reinterpret_cast<float4*>(out_z + (size_t)row * D);
  float s = 0.f;
#pragma unroll
  for (int j = 0; j < D / 4; ++j) {
    float4 e = ep[j];
    float4 o;
    o.x = q[j].x + (e.x - q[j].x);  // STE forward value, reference op order
    o.y = q[j].y + (e.y - q[j].y);
    o.z = q[j].z + (e.z - q[j].z);
    o.w = q[j].w + (e.w - q[j].w);
    op[j] = o;
    float dx = e.x - q[j].x / n;  float dy = e.y - q[j].y / n;
    float dz = e.z - q[j].z / n;  float dw = e.w - q[j].w / n;
    s = fmaf(dx, dx, fmaf(dy, dy, fmaf(dz, dz, fmaf(dw, dw, s))));
  }

#pragma unroll
  for (int off = 32; off > 0; off >>= 1) s += __shfl_down(s, off, 64);
  __shared__ float wsum[4];
  int lane = threadIdx.x & 63, wid = threadIdx.x >> 6;
  if (lane == 0) wsum[wid] = s;
  __syncthreads();
  if (threadIdx.x == 0) {
    float tt = (wsum[0] + wsum[1]) + (wsum[2] + wsum[3]);
    atomicAdd(loss, tt * scale);
  }
}

extern "C" void kernel_launch(void* const* d_in, const int* in_sizes, int n_in,
                              void* d_out, int out_size, void* d_ws, size_t ws_size,
                              hipStream_t stream) {
  const float* z = (const float*)d_in[0];
  const float* emb = (const float*)d_in[1];
  const int N = in_sizes[0] / D;  // 32768
  const int K = in_sizes[1] / D;  // 8192

  float* out = (float*)d_out;
  float* out_z = out;                        // N*D
  float* loss = out + (size_t)N * D;         // 1
  float* out_idx = out + (size_t)N * D + 1;  // N

  // ws layout (~4.1 MB; 8-byte types first for alignment)
  char* w = (char*)d_ws;
  unsigned long long* mpp = (unsigned long long*)w; w += (size_t)KSPLIT * N * 8; // 1 MB
  unsigned long long* mp2 = (unsigned long long*)w; w += (size_t)N * 8;          // 256 KB
  float* en = (float*)w;                         w += (size_t)K * D * 4;         // 1 MB
  float* en_h = (float*)w;                       w += (size_t)K * 4;             // 32 KB
  unsigned short* eswz = (unsigned short*)w;     w += (size_t)K * D * 2 * 2;     // 1 MB
  float* g2 = (float*)w;                         w += (size_t)KSPLIT * N * 4;    // 512 KB
  int* idx_ws = (int*)w;                         w += (size_t)N * 4;             // 128 KB
  int* list = (int*)w;                           w += (size_t)N * 4;             // 128 KB
  int* tick = (int*)w;                           w += 512;
  int* cnt = (int*)w;

  const int nrb = N / 256;   // 128 row-blocks

  k_prep<<<dim3(K / 256), 256, 0, stream>>>(emb, en, en_h, eswz, cnt, loss, tick, nrb);

  k_argmin_mfma<<<dim3(nrb, KSPLIT), 256, 0, stream>>>(
      z, eswz, mpp, g2, tick, idx_ws, list, cnt, mp2, N);

  k_cleanup<<<dim3(2048), 256, 0, stream>>>(z, en, en_h, list, cnt, mp2);

  k_epi<<<dim3(N / 256), 256, 0, stream>>>(
      z, en, idx_ws, mp2, out_z, loss, out_idx, 1.25f / (float)((size_t)N * D));
}